// Round 16
// baseline (292.180 us; speedup 1.0000x reference)
//
#include <hip/hip_runtime.h>
#include <hip/hip_fp16.h>
#include <math.h>

// Problem constants
#define NTT 64
#define NQQ 256
#define NN  16384      // NT*NQ
#define EE  262144     // edges per scale
#define NG  512        // r-grid points for a(t,r) table
#define BKT 48         // padded-CSR bucket stride (mean 16 + 8 sigma)
#define RMAXF 6.0f
#define DRF (RMAXF/(float)(NG-1))
#define INV_DRF ((float)(NG-1)/RMAXF)

// Workspace layout (float-slot offsets)
#define R_OFF     0          // 64*9
#define TR_OFF    576        // 64*3
#define QE_OFF    768        // 64*128 (tab32 pW scratch)
#define G_OFF     8960       // 2*64*64
#define QX_OFF    17152      // 16384*3
#define QF_OFF    66304      // 16384*160
#define N0_OFF    2687744    // full: bucket storage (2*16384*48 ints) ; tab32: num0
#define N1_OFF    5309184    // tab32: num1
#define HIST_OFF  7930624    // 2*16384 (int)
#define START_OFF 7963392    // 2*16384 (int)
#define FILL_OFF  7996160    // 2*16384 (int)
#define SSRC_OFF  8028928    // full: pW tables (2*96*32 float2) ; tab32: ssrc
#define SDST_OFF  8553216    // 2*262144 (int, tab32 fallback)
#define PART_OFF  9102080    // 16384*12
#define BASE_END  9298688
// FULL path: half2 pair-table (PACKED channel order) + half key_f mirrors (PACKED)
#define TABH_OFF  9298688    // 2*64*512*192 half2 = 12582912 float-slots
#define TABH_END  (TABH_OFF + 2*64*NG*192)
#define KFH_OFF   TABH_END   // 2*16e6 halfs = 16e6 float-slots
#define FULL_END  (KFH_OFF + 16000000)
// TAB32 fallback: fp32 table (R4 proven, original layout)
#define TAB_OFF   9298688
#define TAB_END   (TAB_OFF + 2*64*NG*192)

struct __align__(16) H2x4 { __half2 x, y, z, w; };
struct __align__(8)  H2x2 { __half2 x, y; };

// ---------------------------------------------------------------------------
// Kernel 1: prep_AQ — blocks 0..63: rt + qemb + G + qx_flat + qf_t chunk 0
// (+ zero cnt/fill). Blocks 64..65: fold pW. Blocks 66..257 (full path only):
// qf_t chunks 1..3 (3 blocks per t, R recomputed locally — independent).
// ---------------------------------------------------------------------------
__global__ __launch_bounds__(256) void prep_AQ(
    const float* __restrict__ Ts, const float* __restrict__ timev,
    const float* __restrict__ W_qt, const float* __restrict__ b_qt,
    const float* __restrict__ W1_r, const float* __restrict__ b1_r,
    const float* __restrict__ query_x, const float* __restrict__ query_f,
    const float* __restrict__ p00, const float* __restrict__ prest,
    const float* __restrict__ Ws_tp, const float* __restrict__ Wv_tp,
    float* __restrict__ ws, int* __restrict__ histp, int* __restrict__ fillp,
    float2* __restrict__ pW, int split)
{
  int b = blockIdx.x, tid = threadIdx.x;

  if (b >= 64 && b < 66) {
    int ih = b - 64;
    const float* Ws = Ws_tp + ih*96*33;
    const float* Wv = Wv_tp + ih*96*32;
    const float* pp = p00 + ih*64;
    const float* pr = prest + ih*128;
    for (int idx = tid; idx < 3072; idx += 256) {
      int c2 = idx >> 5, o = idx & 31;
      float ps = (c2 < 64) ? pp[c2] : pr[c2];
      float pv = (c2 < 64) ? pr[c2] : pr[c2 + 32];
      pW[ih*3072 + idx] = make_float2(ps * Ws[c2*33 + o + 1], pv * Wv[c2*32 + o]);
    }
    return;
  }

  __shared__ float Rs[12];
  int t, el0, el1;

  if (b < 64) {
    t = b;
    el0 = 0;
    el1 = split ? 10240 : 40960;
  } else {
    int x = b - 66;
    t = x / 3;
    int ch = 1 + (x - t*3);
    el0 = ch*10240;
    el1 = el0 + 10240;
  }

  if (tid == 0) {
    float qw = Ts[t*7+0], qx = Ts[t*7+1], qy = Ts[t*7+2], qz = Ts[t*7+3];
    float nrm = sqrtf(qw*qw + qx*qx + qy*qy + qz*qz);
    qw /= nrm; qx /= nrm; qy /= nrm; qz /= nrm;
    Rs[0] = 1.f - 2.f*(qy*qy + qz*qz); Rs[1] = 2.f*(qx*qy - qw*qz); Rs[2] = 2.f*(qx*qz + qw*qy);
    Rs[3] = 2.f*(qx*qy + qw*qz); Rs[4] = 1.f - 2.f*(qx*qx + qz*qz); Rs[5] = 2.f*(qy*qz - qw*qx);
    Rs[6] = 2.f*(qx*qz - qw*qy); Rs[7] = 2.f*(qy*qz + qw*qx); Rs[8] = 1.f - 2.f*(qx*qx + qy*qy);
    Rs[9] = Ts[t*7+4]; Rs[10] = Ts[t*7+5]; Rs[11] = Ts[t*7+6];
  }

  if (b < 64) {
    __shared__ float te[128];
    __shared__ float qe[128];

    {
      int base = t*512;
      histp[base + tid] = 0;        histp[base + 256 + tid] = 0;
      fillp[base + tid] = 0;        fillp[base + 256 + tid] = 0;
    }

    float tt = timev[t];
    if (tid < 128) {
      int h = tid & 63;
      float fr = __expf(-logf(10000.f) * (float)h / 63.f);
      float a = tt * fr;
      te[tid] = (tid < 64) ? sinf(a) : cosf(a);
    }
    __syncthreads();
    if (tid == 0) {
      float* R = ws + R_OFF + t*9;
      #pragma unroll
      for (int i = 0; i < 9; i++) R[i] = Rs[i];
      ws[TR_OFF + t*3 + 0] = Rs[9];
      ws[TR_OFF + t*3 + 1] = Rs[10];
      ws[TR_OFF + t*3 + 2] = Rs[11];
    }
    if (tid < 128) {
      float acc = b_qt[tid];
      #pragma unroll 4
      for (int k = 0; k < 128; k++) acc += te[k] * W_qt[k*128 + tid];
      qe[tid] = acc;
    }
    __syncthreads();
    if (tid < 128) {
      int sidx = tid >> 6, o = tid & 63;
      const float* W1 = W1_r + sidx*136*64;
      float acc = b1_r[sidx*64 + o];
      #pragma unroll 4
      for (int k = 0; k < 128; k++) acc += qe[k] * W1[(8+k)*64 + o];
      ws[G_OFF + sidx*4096 + t*64 + o] = acc;
    }
    for (int el = tid; el < 768; el += 256) {
      int q = el / 3, i = el - q*3;
      const float* x = query_x + q*3;
      ws[QX_OFF + t*768 + el] = Rs[i*3+0]*x[0] + Rs[i*3+1]*x[1] + Rs[i*3+2]*x[2] + Rs[9+i];
    }
  } else {
    __syncthreads();
  }

  for (int el = el0 + tid; el < el1; el += 256) {
    int q = el / 160, j = el - q*160;
    float v;
    if (j < 64) {
      v = query_f[q*160 + j];
    } else {
      int c = (j - 64) / 3, i = (j - 64) - c*3;
      const float* qv = query_f + q*160 + 64 + c*3;
      v = Rs[i*3+0]*qv[0] + Rs[i*3+1]*qv[1] + Rs[i*3+2]*qv[2];
    }
    ws[QF_OFF + (size_t)t*40960 + el] = v;
  }
}

// ---------------------------------------------------------------------------
// Kernel 2 (FULL path): aux_fused — conv_kf (blocks <6250) + padded-CSR
// bucket (6250..7274) + build_tabH (7274..7786, sidx = blockIdx.y).
// All branches low-VGPR (~40-50); build's FMA overlaps conv's BW stalls.
// ---------------------------------------------------------------------------
__global__ __launch_bounds__(256) void aux_fused(
    const float* __restrict__ kf0, const float* __restrict__ kf1,
    __half* __restrict__ o0, __half* __restrict__ o1,
    const int* __restrict__ es0, const int* __restrict__ ed0,
    const int* __restrict__ es1, const int* __restrict__ ed1,
    int* __restrict__ cnt, int* __restrict__ bucket,
    const float* __restrict__ W1_r, const float* __restrict__ W2_r,
    const float* __restrict__ b2_r, const float* __restrict__ Gall,
    __half2* __restrict__ tabH)
{
  int sc = blockIdx.y, tid = threadIdx.x;

  if (blockIdx.x < 6250) {
    // ---- conv_kf: LDS-staged packed half mirror ----
    __shared__ float stage[2560];
    const float* src = sc ? kf1 : kf0;
    __half* dst = sc ? o1 : o0;
    size_t base = (size_t)blockIdx.x * 2560;
    #pragma unroll
    for (int it = 0; it < 10; it++) stage[it*256 + tid] = src[base + it*256 + tid];
    __syncthreads();
    #pragma unroll
    for (int it = 0; it < 10; it++) {
      int idx = it*256 + tid;
      int n = idx / 160;
      int j = idx - n*160;
      int orig;
      if (j < 32) {
        orig = 32 + j;
      } else {
        int qq = (j - 32) >> 2, rr = (j - 32) & 3;
        orig = (rr < 3) ? (64 + 3*qq + rr) : qq;
      }
      dst[base + idx] = __float2half_rn(stage[n*160 + orig]);
    }
  } else if (blockIdx.x < 7274) {
    // ---- bucket: padded CSR, atomic count IS the histogram ----
    int b = blockIdx.x - 6250;
    const int* es = sc ? es1 : es0;
    const int* ed = sc ? ed1 : ed0;
    int e = b*256 + tid;
    int d = ed[e];
    int pos = atomicAdd(cnt + sc*NN + d, 1);
    if (pos < BKT) bucket[((size_t)sc*NN + d)*BKT + pos] = es[e];
  } else {
    // ---- build_tabH: packed half2 pair-table ----
    int b = blockIdx.x - 7274;          // 0..511
    int t = b & 63, gblk = b >> 6;      // 64 t x 8 gblk
    int sidx = sc;
    const float* W1 = W1_r + sidx*136*64;
    const float* W2 = W2_r + sidx*64*192;
    const float* b2 = b2_r + sidx*192;
    const float* G  = Gall + sidx*4096 + t*64;
    __shared__ float hb[4][64];
    __shared__ float rows[5][192];
    int gl = gblk*64;

    if (tid < 64) {
      float r = (float)gl * DRF;
      float a = G[tid];
      #pragma unroll
      for (int j = 0; j < 8; j++) {
        float dd = r - (float)j*(4.f/7.f);
        a += __expf(-4.f*dd*dd) * W1[j*64 + tid];
      }
      hb[0][tid] = a / (1.f + __expf(-a));
    }
    __syncthreads();
    if (tid < 192) {
      float acc = b2[tid];
      #pragma unroll
      for (int k = 0; k < 64; k++) acc += hb[0][k] * W2[k*192 + tid];
      rows[0][tid] = acc;
    }
    __syncthreads();

    for (int g = 0; g < 16; g++) {
      {
        int gg = tid >> 6, k = tid & 63;
        float r = (float)(gl + 4*g + 1 + gg) * DRF;
        float a = G[k];
        #pragma unroll
        for (int j = 0; j < 8; j++) {
          float dd = r - (float)j*(4.f/7.f);
          a += __expf(-4.f*dd*dd) * W1[j*64 + k];
        }
        hb[gg][k] = a / (1.f + __expf(-a));
      }
      __syncthreads();
      #pragma unroll
      for (int it = 0; it < 3; it++) {
        int item = it*256 + tid;
        int rr = item / 192, o = item - rr*192;
        float acc = b2[o];
        #pragma unroll
        for (int k = 0; k < 64; k++) acc += hb[rr][k] * W2[k*192 + o];
        rows[1 + rr][o] = acc;
      }
      __syncthreads();
      __half2* T = tabH + ((size_t)(sidx*64 + t)*NG + gl + 4*g)*192;
      #pragma unroll
      for (int it = 0; it < 3; it++) {
        int item = it*256 + tid;
        int pr = item / 192, o = item - pr*192;
        int src = (o < 64) ? o : (64 + 32*((o-64)&3) + ((o-64)>>2));
        T[(size_t)pr*192 + o] = __floats2half2_rn(rows[pr][src], rows[pr+1][src]);
      }
      __syncthreads();
      if (tid < 192) rows[0][tid] = rows[4][tid];
      __syncthreads();
    }
  }
}

// ---------------------------------------------------------------------------
// Kernel 3 (FULL path): node-centric edge accumulation + tp_head inline
// (R13-proven form: no software pipeline; TLP hides gather latency)
// ---------------------------------------------------------------------------
__global__ __launch_bounds__(256) void edge_head_kernel(
    const float* __restrict__ kx0, const float* __restrict__ kx1,
    const __half* __restrict__ kfh0, const __half* __restrict__ kfh1,
    const int* __restrict__ bucket, const int* __restrict__ hist,
    const __half2* __restrict__ tabH, const float* __restrict__ qx_flat,
    const float* __restrict__ qf_t, const float* __restrict__ Rtab,
    const float* __restrict__ query_x, const float* __restrict__ query_w,
    const float2* __restrict__ pW,
    float* __restrict__ part)
{
  __shared__ float sb[4][96];
  __shared__ float vb[4][96][3];
  int wid = threadIdx.x >> 6, lane = threadIdx.x & 63;
  int n = blockIdx.x*4 + wid;
  int t = n >> 8, q = n & 255;
  int lo = lane & 31;
  bool isHi = lane >= 32;
  float qxv0 = qx_flat[n*3+0], qxv1 = qx_flat[n*3+1], qxv2 = qx_flat[n*3+2];
  int ksAddr = isHi ? (lane - 32) : (32 + 4*lane + 3);

  float kfs = 0.f, kv0 = 0.f, kv1 = 0.f, kv2 = 0.f;

  #pragma unroll 1
  for (int sc = 0; sc < 2; sc++) {
    const float* key_x = sc ? kx1 : kx0;
    const __half* kfb  = sc ? kfh1 : kfh0;
    const __half2* Tb  = tabH + (size_t)sc*(64*NG*192);
    int cntT = hist[sc*NN + n];
    int cnt = cntT < BKT ? cntT : BKT;
    const int* srcp = bucket + ((size_t)sc*NN + n)*BKT;

    float accs = 0.f, accM = 0.f, av0 = 0.f, av1 = 0.f, av2 = 0.f;

    for (int e = 0; e < cnt; e += 2) {
      int eMy = e + (isHi ? 1 : 0);
      float wMy = (eMy < cnt) ? 1.f : 0.f;
      int eCl = (eMy < cnt) ? eMy : (cnt - 1);
      int sMy = srcp[eCl];

      float rel0 = key_x[sMy*3+0] - qxv0;
      float rel1 = key_x[sMy*3+1] - qxv1;
      float rel2 = key_x[sMy*3+2] - qxv2;
      float r = sqrtf(rel0*rel0 + rel1*rel1 + rel2*rel2);
      float rinv = 1.f / (r + 1e-8f);
      float dir0 = rel0*rinv, dir1 = rel1*rinv, dir2 = rel2*rinv;
      float x = fminf(r, RMAXF) * INV_DRF;
      int i = (int)x; if (i > NG-2) i = NG-2;
      float fMy = x - (float)i;
      int rowMy = t*NG + i;

      int   sOth   = __shfl_xor(sMy, 32);
      int   rowOth = __shfl_xor(rowMy, 32);
      float fOth   = __shfl_xor(fMy, 32);
      float wOth   = isHi ? 1.f : ((e + 1 < cnt) ? 1.f : 0.f);

      const __half2* thMy  = Tb + (size_t)rowMy*192;
      const __half2* thOth = Tb + (size_t)rowOth*192;
      const __half*  kfMy  = kfb + (size_t)sMy*160;
      const __half*  kfOth = kfb + (size_t)sOth*160;

      // scalar channel `lane`, both edges
      float2 u0m = __half22float2(thMy[lane]);
      float a0m = fmaf(fMy, u0m.y - u0m.x, u0m.x);
      float ksm = __half2float(kfMy[ksAddr]);
      float2 u0o = __half22float2(thOth[lane]);
      float a0o = fmaf(fOth, u0o.y - u0o.x, u0o.x);
      float kso = __half2float(kfOth[ksAddr]);
      accs += wMy*a0m*ksm + wOth*a0o*kso;

      // vec channel `lo` of MY edge: one 16B + one 8B packed load
      H2x4 pq = *(const H2x4*)(thMy + 64 + 4*lo);
      float2 ua = __half22float2(pq.x);
      float2 ub = __half22float2(pq.y);
      float2 uc = __half22float2(pq.z);
      float2 ud = __half22float2(pq.w);
      float a1 = fmaf(fMy, ua.y - ua.x, ua.x);
      float a2 = fmaf(fMy, ub.y - ub.x, ub.x);
      float a3 = fmaf(fMy, uc.y - uc.x, uc.x);
      float a4 = fmaf(fMy, ud.y - ud.x, ud.x);
      H2x2 kq = *(const H2x2*)(kfMy + 32 + 4*lo);
      float2 kA = __half22float2(kq.x);
      float2 kB = __half22float2(kq.y);
      float k0 = kA.x * wMy, k1 = kA.y * wMy, k2 = kB.x * wMy, ksv = kB.y * wMy;
      float dt = k0*dir0 + k1*dir1 + k2*dir2;
      accM += a3*dt;
      float cr0 = k1*dir2 - k2*dir1;
      float cr1 = k2*dir0 - k0*dir2;
      float cr2 = k0*dir1 - k1*dir0;
      float sv = a2*ksv;
      av0 += a1*k0 + sv*dir0 + a4*cr0;
      av1 += a1*k1 + sv*dir1 + a4*cr1;
      av2 += a1*k2 + sv*dir2 + a4*cr2;
    }

    float mT  = accM + __shfl_down(accM, 32);
    float v0T = av0 + __shfl_down(av0, 32);
    float v1T = av1 + __shfl_down(av1, 32);
    float v2T = av2 + __shfl_down(av2, 32);
    float ic = 1.f / ((float)cntT + 1e-8f);
    kfs += ic * (accs + (isHi ? 0.f : mT));
    kv0 += ic * v0T; kv1 += ic * v1T; kv2 += ic * v2T;
  }

  // ---- tp_head phase 1 ----
  const float* qf = qf_t + (size_t)n*160;
  sb[wid][lane] = kfs * qf[lane];
  if (!isHi) {
    float qs = qf[lane];
    float q0 = qf[64+3*lane+0], q1 = qf[64+3*lane+1], q2 = qf[64+3*lane+2];
    sb[wid][64+lane] = kv0*q0 + kv1*q1 + kv2*q2;
    vb[wid][lane][0] = kv0*qs;  vb[wid][lane][1] = kv1*qs;  vb[wid][lane][2] = kv2*qs;
    vb[wid][32+lane][0] = kfs*q0; vb[wid][32+lane][1] = kfs*q1; vb[wid][32+lane][2] = kfs*q2;
    vb[wid][64+lane][0] = kv1*q2 - kv2*q1;
    vb[wid][64+lane][1] = kv2*q0 - kv0*q2;
    vb[wid][64+lane][2] = kv0*q1 - kv1*q0;
  }
  __syncthreads();

  // ---- tp_head phase 2 (prefolded weights) ----
  int ih = lane >> 5, o = lane & 31;
  const float2* pWh = pW + ih*3072 + o;
  float g = 0.f, v0 = 0.f, v1 = 0.f, v2 = 0.f;
  #pragma unroll 4
  for (int c2 = 0; c2 < 96; c2++) {
    float2 wv = pWh[c2*32];
    g += sb[wid][c2] * wv.x;
    v0 += vb[wid][c2][0] * wv.y;
    v1 += vb[wid][c2][1] * wv.y;
    v2 += vb[wid][c2][2] * wv.y;
  }
  g = 1.f / (1.f + __expf(-g));
  v0 *= g; v1 *= g; v2 *= g;
  #pragma unroll
  for (int m = 16; m >= 1; m >>= 1) {
    v0 += __shfl_xor(v0, m, 32);
    v1 += __shfl_xor(v1, m, 32);
    v2 += __shfl_xor(v2, m, 32);
  }
  if (o == 0) {
    v0 *= (1.f/32.f); v1 *= (1.f/32.f); v2 *= (1.f/32.f);
    const float* R = Rtab + t*9;
    float r0 = R[0]*v0 + R[3]*v1 + R[6]*v2;
    float r1 = R[1]*v0 + R[4]*v1 + R[7]*v2;
    float r2 = R[2]*v0 + R[5]*v1 + R[8]*v2;
    float w = query_w[q];
    float* pout = part + (size_t)n*12;
    if (ih == 0) {
      pout[0] = w*r0; pout[1] = w*r1; pout[2] = w*r2;
      float x0 = query_x[q*3+0], x1 = query_x[q*3+1], x2 = query_x[q*3+2];
      pout[3] = w*(x1*r2 - x2*r1);
      pout[4] = w*(x2*r0 - x0*r2);
      pout[5] = w*(x0*r1 - x1*r0);
    } else {
      pout[6] = w*r0; pout[7] = w*r1; pout[8] = w*r2;
    }
  }
}

// ===========================================================================
// TAB32 fallback kernels (R4-proven path)
// ===========================================================================
__global__ __launch_bounds__(256) void hist_kernel(
    const int* __restrict__ ed0, const int* __restrict__ ed1,
    int* __restrict__ hist)
{
  int sc = blockIdx.y;
  const int* ed = sc ? ed1 : ed0;
  int e = blockIdx.x*256 + threadIdx.x;
  atomicAdd(hist + sc*NN + ed[e], 1);
}

__global__ __launch_bounds__(1024) void scan_kernel(
    const int* __restrict__ hist, int* __restrict__ start)
{
  int sc = blockIdx.x;
  const int* h = hist + sc*NN;
  int* st = start + sc*NN;
  __shared__ int lds[1024];
  int tid = threadIdx.x;
  int loc[16]; int s = 0;
  #pragma unroll
  for (int j = 0; j < 16; j++) { loc[j] = s; s += h[tid*16 + j]; }
  lds[tid] = s;
  __syncthreads();
  for (int off = 1; off < 1024; off <<= 1) {
    int v = lds[tid];
    int u = (tid >= off) ? lds[tid - off] : 0;
    __syncthreads();
    lds[tid] = v + u;
    __syncthreads();
  }
  int base = lds[tid] - s;
  #pragma unroll
  for (int j = 0; j < 16; j++) st[tid*16 + j] = base + loc[j];
}

__global__ __launch_bounds__(256) void scatter_kernel(
    const int* __restrict__ es0, const int* __restrict__ ed0,
    const int* __restrict__ es1, const int* __restrict__ ed1,
    const int* __restrict__ start, int* __restrict__ fill,
    int* __restrict__ ssrc, int* __restrict__ sdst)
{
  int sc = blockIdx.y;
  const int* es = sc ? es1 : es0;
  const int* ed = sc ? ed1 : ed0;
  int e = blockIdx.x*256 + threadIdx.x;
  int d = ed[e];
  int pos = start[sc*NN + d] + atomicAdd(fill + sc*NN + d, 1);
  ssrc[sc*EE + pos] = es[e];
  sdst[sc*EE + pos] = d;
}

__global__ __launch_bounds__(256) void build_tab(
    const float* __restrict__ W1_r, const float* __restrict__ W2_r,
    const float* __restrict__ b2_r, const float* __restrict__ Gall,
    float* __restrict__ tab)
{
  int t = blockIdx.x, gblk = blockIdx.y, sidx = blockIdx.z;
  const float* W1 = W1_r + sidx*136*64;
  const float* W2 = W2_r + sidx*64*192;
  const float* b2 = b2_r + sidx*192;
  const float* G  = Gall + sidx*4096 + t*64;
  float* T = tab + (((size_t)sidx*64 + t)*NG)*192;
  __shared__ float hb[4][64];
  int tid = threadIdx.x;
  for (int g4 = 0; g4 < 16; g4++) {
    int gl = gblk*64 + g4*4;
    {
      int gg = tid >> 6;
      int k  = tid & 63;
      float r = (float)(gl + gg) * DRF;
      float a = G[k];
      #pragma unroll
      for (int j = 0; j < 8; j++) {
        float dd = r - (float)j*(4.f/7.f);
        a += __expf(-4.f*dd*dd) * W1[j*64 + k];
      }
      hb[gg][k] = a / (1.f + __expf(-a));
    }
    __syncthreads();
    #pragma unroll
    for (int it = 0; it < 3; it++) {
      int item = it*256 + tid;
      int gg = item / 192;
      int o  = item - gg*192;
      float acc = b2[o];
      #pragma unroll
      for (int k = 0; k < 64; k++) acc += hb[gg][k] * W2[k*192 + o];
      T[(size_t)(gl + gg)*192 + o] = acc;
    }
    __syncthreads();
  }
}

#define SEGRED(v) { float _t; \
  _t = __shfl_down(v, 1);  v += mm0 ? _t : 0.f; \
  _t = __shfl_down(v, 2);  v += mm1 ? _t : 0.f; \
  _t = __shfl_down(v, 4);  v += mm2 ? _t : 0.f; \
  _t = __shfl_down(v, 8);  v += mm3 ? _t : 0.f; \
  _t = __shfl_down(v, 16); v += mm4 ? _t : 0.f; \
  _t = __shfl_down(v, 32); v += mm5 ? _t : 0.f; }

#define SEGMASKS() \
  int dn; \
  dn = __shfl_down(d, 1);  bool mm0 = (lane + 1  < 64) && (dn == d); \
  dn = __shfl_down(d, 2);  bool mm1 = (lane + 2  < 64) && (dn == d); \
  dn = __shfl_down(d, 4);  bool mm2 = (lane + 4  < 64) && (dn == d); \
  dn = __shfl_down(d, 8);  bool mm3 = (lane + 8  < 64) && (dn == d); \
  dn = __shfl_down(d, 16); bool mm4 = (lane + 16 < 64) && (dn == d); \
  dn = __shfl_down(d, 32); bool mm5 = (lane + 32 < 64) && (dn == d); \
  int dp = __shfl_up(d, 1); \
  bool head = (lane == 0) || (dp != d);

#define INTERP4(dst, off) { \
  float4 _A = *(const float4*)(t0 + (off)); \
  float4 _B = *(const float4*)(t1 + (off)); \
  dst[0] = _A.x + f*(_B.x - _A.x); \
  dst[1] = _A.y + f*(_B.y - _A.y); \
  dst[2] = _A.z + f*(_B.z - _A.z); \
  dst[3] = _A.w + f*(_B.w - _A.w); }

__global__ __launch_bounds__(256) void edge_tab_kernel(
    const float* __restrict__ kx0, const float* __restrict__ kf0,
    const float* __restrict__ kx1, const float* __restrict__ kf1,
    const int* __restrict__ ssrc, const int* __restrict__ sdst,
    const float* __restrict__ tab, const float* __restrict__ qx_flat,
    float* __restrict__ num0, float* __restrict__ num1)
{
  int sc = blockIdx.y;
  const float* key_x = sc ? kx1 : kx0;
  const float* key_f = sc ? kf1 : kf0;
  const float* Tb = tab + (size_t)sc*64*NG*192;
  float* numbuf = sc ? num1 : num0;

  int p = blockIdx.x*256 + threadIdx.x;
  int lane = threadIdx.x & 63;
  int s = ssrc[sc*EE + p], d = sdst[sc*EE + p];

  const float* qx = qx_flat + d*3;
  float rel0 = key_x[s*3+0] - qx[0];
  float rel1 = key_x[s*3+1] - qx[1];
  float rel2 = key_x[s*3+2] - qx[2];
  float r = sqrtf(rel0*rel0 + rel1*rel1 + rel2*rel2);
  float rinv = 1.f / (r + 1e-8f);
  float dir0 = rel0*rinv, dir1 = rel1*rinv, dir2 = rel2*rinv;

  int t = d >> 8;
  float x = fminf(r, RMAXF) * INV_DRF;
  int i = (int)x; if (i > NG-2) i = NG-2;
  float f = x - (float)i;
  const float* t0 = Tb + ((size_t)(t*NG + i))*192;
  const float* t1 = t0 + 192;

  SEGMASKS();

  const float* kf = key_f + (size_t)s * 160;
  float* nrow = numbuf + (size_t)d * 160;

  #pragma unroll 1
  for (int cq = 0; cq < 8; cq++) {
    int c = 4*cq;
    float a0v[4], a1v[4], a2v[4], a3v[4], a4v[4];
    INTERP4(a0v, c);
    INTERP4(a1v, 64 + c);
    INTERP4(a2v, 96 + c);
    INTERP4(a3v, 128 + c);
    INTERP4(a4v, 160 + c);
    float4 ksq = *(const float4*)(kf + c);
    float ksv[4] = {ksq.x, ksq.y, ksq.z, ksq.w};
    const float* kvp = kf + 64 + 3*c;
    float2 v0 = *(const float2*)(kvp + 0);
    float2 v1 = *(const float2*)(kvp + 2);
    float2 v2 = *(const float2*)(kvp + 4);
    float2 v3 = *(const float2*)(kvp + 6);
    float2 v4 = *(const float2*)(kvp + 8);
    float2 v5 = *(const float2*)(kvp + 10);
    float kvx[4] = {v0.x, v1.y, v3.x, v4.y};
    float kvy[4] = {v0.y, v2.x, v3.y, v5.x};
    float kvz[4] = {v1.x, v2.y, v4.x, v5.y};
    #pragma unroll
    for (int u = 0; u < 4; u++) {
      float ks = ksv[u];
      float k0 = kvx[u], k1 = kvy[u], k2 = kvz[u];
      float dt = k0*dir0 + k1*dir1 + k2*dir2;
      float ms = a0v[u]*ks + a3v[u]*dt;
      float cr0 = k1*dir2 - k2*dir1;
      float cr1 = k2*dir0 - k0*dir2;
      float cr2 = k0*dir1 - k1*dir0;
      float sv = a2v[u]*ks;
      float m0 = a1v[u]*k0 + sv*dir0 + a4v[u]*cr0;
      float m1 = a1v[u]*k1 + sv*dir1 + a4v[u]*cr1;
      float m2 = a1v[u]*k2 + sv*dir2 + a4v[u]*cr2;
      SEGRED(ms); SEGRED(m0); SEGRED(m1); SEGRED(m2);
      if (head) {
        int cc = c + u;
        atomicAdd(nrow + cc, ms);
        atomicAdd(nrow + 64 + 3*cc + 0, m0);
        atomicAdd(nrow + 64 + 3*cc + 1, m1);
        atomicAdd(nrow + 64 + 3*cc + 2, m2);
      }
    }
  }
  #pragma unroll 1
  for (int cq = 0; cq < 8; cq++) {
    int c = 32 + 4*cq;
    float a0v[4];
    INTERP4(a0v, c);
    float4 ksq = *(const float4*)(kf + c);
    float ksv[4] = {ksq.x, ksq.y, ksq.z, ksq.w};
    #pragma unroll
    for (int u = 0; u < 4; u++) {
      float ms = a0v[u]*ksv[u];
      SEGRED(ms);
      if (head) atomicAdd(nrow + c + u, ms);
    }
  }
}

__global__ __launch_bounds__(256) void head_kernel(
    const float* __restrict__ num0, const float* __restrict__ num1,
    const int* __restrict__ h0, const int* __restrict__ h1c,
    const float* __restrict__ qf_t, const float* __restrict__ Rtab,
    const float* __restrict__ query_x, const float* __restrict__ query_w,
    const float* __restrict__ p00, const float* __restrict__ prest,
    const float* __restrict__ Ws_tp, const float* __restrict__ Wv_tp,
    float* __restrict__ part)
{
  int wid = threadIdx.x >> 6;
  int lane = threadIdx.x & 63;
  int n = blockIdx.x*4 + wid;
  int t = n >> 8, q = n & 255;
  __shared__ float sb[4][96];
  __shared__ float vb[4][96][3];
  const float* n0 = num0 + (size_t)n*160;
  const float* n1 = num1 + (size_t)n*160;
  const float* qf = qf_t + (size_t)n*160;
  float ic0 = 1.f / ((float)h0[n] + 1e-8f);
  float ic1 = 1.f / ((float)h1c[n] + 1e-8f);
  int c = lane;
  if (c < 64) sb[wid][c] = (n0[c]*ic0 + n1[c]*ic1) * qf[c];
  if (c < 32) {
    float ks = n0[c]*ic0 + n1[c]*ic1;
    float qs = qf[c];
    float k0 = n0[64+3*c+0]*ic0 + n1[64+3*c+0]*ic1;
    float k1 = n0[64+3*c+1]*ic0 + n1[64+3*c+1]*ic1;
    float k2 = n0[64+3*c+2]*ic0 + n1[64+3*c+2]*ic1;
    float q0 = qf[64+3*c+0], q1 = qf[64+3*c+1], q2 = qf[64+3*c+2];
    sb[wid][64+c] = k0*q0 + k1*q1 + k2*q2;
    vb[wid][c][0] = k0*qs;  vb[wid][c][1] = k1*qs;  vb[wid][c][2] = k2*qs;
    vb[wid][32+c][0] = ks*q0;  vb[wid][32+c][1] = ks*q1;  vb[wid][32+c][2] = ks*q2;
    vb[wid][64+c][0] = k1*q2 - k2*q1;
    vb[wid][64+c][1] = k2*q0 - k0*q2;
    vb[wid][64+c][2] = k0*q1 - k1*q0;
  }
  __syncthreads();

  int i = lane >> 5, o = lane & 31;
  const float* Ws = Ws_tp + i*96*33;
  const float* Wv = Wv_tp + i*96*32;
  const float* pp = p00 + i*64;
  const float* pr = prest + i*128;
  float g = 0.f, v0 = 0.f, v1 = 0.f, v2 = 0.f;
  for (int c2 = 0; c2 < 96; c2++) {
    float ps = (c2 < 64) ? pp[c2] : pr[c2];
    float pv = (c2 < 64) ? pr[c2] : pr[c2 + 32];
    g += sb[wid][c2] * ps * Ws[c2*33 + o + 1];
    float pw = pv * Wv[c2*32 + o];
    v0 += vb[wid][c2][0] * pw;
    v1 += vb[wid][c2][1] * pw;
    v2 += vb[wid][c2][2] * pw;
  }
  g = 1.f / (1.f + __expf(-g));
  v0 *= g; v1 *= g; v2 *= g;
  #pragma unroll
  for (int m = 16; m >= 1; m >>= 1) {
    v0 += __shfl_xor(v0, m, 32);
    v1 += __shfl_xor(v1, m, 32);
    v2 += __shfl_xor(v2, m, 32);
  }
  if (o == 0) {
    v0 *= (1.f/32.f); v1 *= (1.f/32.f); v2 *= (1.f/32.f);
    const float* R = Rtab + t*9;
    float r0 = R[0]*v0 + R[3]*v1 + R[6]*v2;
    float r1 = R[1]*v0 + R[4]*v1 + R[7]*v2;
    float r2 = R[2]*v0 + R[5]*v1 + R[8]*v2;
    float w = query_w[q];
    float* pout = part + (size_t)n*12;
    if (i == 0) {
      pout[0] = w*r0; pout[1] = w*r1; pout[2] = w*r2;
      float x0 = query_x[q*3+0], x1 = query_x[q*3+1], x2 = query_x[q*3+2];
      pout[3] = w*(x1*r2 - x2*r1);
      pout[4] = w*(x2*r0 - x0*r2);
      pout[5] = w*(x0*r1 - x1*r0);
    } else {
      pout[6] = w*r0; pout[7] = w*r1; pout[8] = w*r2;
    }
  }
}

// ---------------------------------------------------------------------------
// Kernel 4: reduce partials over q (256 per template)
// ---------------------------------------------------------------------------
__global__ __launch_bounds__(256) void final_kernel(
    const float* __restrict__ part, float* __restrict__ out)
{
  int t = blockIdx.x, q = threadIdx.x;
  const float* pr = part + ((size_t)(t*256 + q))*12;
  float v[9];
  #pragma unroll
  for (int i = 0; i < 9; i++) v[i] = pr[i];
  #pragma unroll
  for (int m = 32; m >= 1; m >>= 1) {
    #pragma unroll
    for (int i = 0; i < 9; i++) v[i] += __shfl_down(v[i], m);
  }
  __shared__ float lds[4][9];
  int w = q >> 6, l = q & 63;
  if (l == 0) {
    #pragma unroll
    for (int i = 0; i < 9; i++) lds[w][i] = v[i];
  }
  __syncthreads();
  if (q == 0) {
    float o[9];
    #pragma unroll
    for (int i = 0; i < 9; i++) o[i] = lds[0][i] + lds[1][i] + lds[2][i] + lds[3][i];
    out[t*3+0] = o[3] + o[6];
    out[t*3+1] = o[4] + o[7];
    out[t*3+2] = o[5] + o[8];
    out[192 + t*3+0] = o[0];
    out[192 + t*3+1] = o[1];
    out[192 + t*3+2] = o[2];
  }
}

// ---------------------------------------------------------------------------
extern "C" void kernel_launch(void* const* d_in, const int* in_sizes, int n_in,
                              void* d_out, int out_size, void* d_ws, size_t ws_size,
                              hipStream_t stream)
{
  const float* Ts      = (const float*)d_in[0];
  const float* timev   = (const float*)d_in[1];
  const float* query_x = (const float*)d_in[2];
  const float* query_f = (const float*)d_in[3];
  const float* query_w = (const float*)d_in[4];
  const float* key_x_0 = (const float*)d_in[5];
  const float* key_f_0 = (const float*)d_in[6];
  const float* key_x_1 = (const float*)d_in[7];
  const float* key_f_1 = (const float*)d_in[8];
  const int*   es0     = (const int*)d_in[9];
  const int*   ed0     = (const int*)d_in[10];
  const int*   es1     = (const int*)d_in[11];
  const int*   ed1     = (const int*)d_in[12];
  const float* W_qt    = (const float*)d_in[13];
  const float* b_qt    = (const float*)d_in[14];
  const float* W1_r    = (const float*)d_in[15];
  const float* b1_r    = (const float*)d_in[16];
  const float* W2_r    = (const float*)d_in[17];
  const float* b2_r    = (const float*)d_in[18];
  const float* p00     = (const float*)d_in[19];
  const float* prest   = (const float*)d_in[20];
  const float* Ws_tp   = (const float*)d_in[21];
  const float* Wv_tp   = (const float*)d_in[22];
  float* ws  = (float*)d_ws;
  float* out = (float*)d_out;

  int* histp  = (int*)(ws + HIST_OFF);
  int* startp = (int*)(ws + START_OFF);
  int* fillp  = (int*)(ws + FILL_OFF);
  int* ssrcp  = (int*)(ws + SSRC_OFF);
  int* sdstp  = (int*)(ws + SDST_OFF);
  int* bucketp = (int*)(ws + N0_OFF);
  float2* pWp  = (float2*)(ws + SSRC_OFF);

  bool full  = ws_size >= (size_t)FULL_END * sizeof(float);
  bool tab32 = !full && ws_size >= (size_t)TAB_END * sizeof(float);

  if (full) {
    __half* kfh0 = (__half*)(ws + KFH_OFF);
    __half* kfh1 = kfh0 + 16000000;
    __half2* tabH = (__half2*)(ws + TABH_OFF);

    prep_AQ<<<258, 256, 0, stream>>>(Ts, timev, W_qt, b_qt, W1_r, b1_r,
                                     query_x, query_f, p00, prest, Ws_tp, Wv_tp,
                                     ws, histp, fillp, pWp, 1);
    aux_fused<<<dim3(7786, 2), 256, 0, stream>>>(
        key_f_0, key_f_1, kfh0, kfh1,
        es0, ed0, es1, ed1, histp, bucketp,
        W1_r, W2_r, b2_r, ws + G_OFF, tabH);
    edge_head_kernel<<<4096, 256, 0, stream>>>(
        key_x_0, key_x_1, kfh0, kfh1,
        bucketp, histp, tabH, ws + QX_OFF,
        ws + QF_OFF, ws + R_OFF,
        query_x, query_w, pWp,
        ws + PART_OFF);
  } else if (tab32) {
    hipMemsetAsync(ws + N0_OFF, 0, (size_t)(2*NN*160) * sizeof(float), stream);
    prep_AQ<<<64, 256, 0, stream>>>(Ts, timev, W_qt, b_qt, W1_r, b1_r,
                                    query_x, query_f, p00, prest, Ws_tp, Wv_tp,
                                    ws, histp, fillp, (float2*)(ws + QE_OFF), 0);
    hist_kernel<<<dim3(1024, 2), 256, 0, stream>>>(ed0, ed1, histp);
    scan_kernel<<<2, 1024, 0, stream>>>(histp, startp);
    scatter_kernel<<<dim3(1024, 2), 256, 0, stream>>>(
        es0, ed0, es1, ed1, startp, fillp, ssrcp, sdstp);
    build_tab<<<dim3(64, 8, 2), 256, 0, stream>>>(
        W1_r, W2_r, b2_r, ws + G_OFF, ws + TAB_OFF);
    edge_tab_kernel<<<dim3(1024, 2), 256, 0, stream>>>(
        key_x_0, key_f_0, key_x_1, key_f_1,
        ssrcp, sdstp, ws + TAB_OFF, ws + QX_OFF,
        ws + N0_OFF, ws + N1_OFF);
    head_kernel<<<4096, 256, 0, stream>>>(
        ws + N0_OFF, ws + N1_OFF, histp, histp + NN,
        ws + QF_OFF, ws + R_OFF,
        query_x, query_w, p00, prest, Ws_tp, Wv_tp, ws + PART_OFF);
  }

  final_kernel<<<64, 256, 0, stream>>>(ws + PART_OFF, out);
}

// Round 17
// 280.387 us; speedup vs baseline: 1.0421x; 1.0421x over previous
//
#include <hip/hip_runtime.h>
#include <hip/hip_fp16.h>
#include <math.h>

// Problem constants
#define NTT 64
#define NQQ 256
#define NN  16384      // NT*NQ
#define EE  262144     // edges per scale
#define NG  512        // r-grid points for a(t,r) table
#define BKT 48         // padded-CSR bucket stride (mean 16 + 8 sigma)
#define RMAXF 6.0f
#define DRF (RMAXF/(float)(NG-1))
#define INV_DRF ((float)(NG-1)/RMAXF)

// Workspace layout (float-slot offsets)
#define R_OFF     0          // 64*9
#define TR_OFF    576        // 64*3
#define QE_OFF    768        // 64*128 (tab32 pW scratch)
#define G_OFF     8960       // 2*64*64
#define QX_OFF    17152      // 16384*3
#define QF_OFF    66304      // 16384*160
#define N0_OFF    2687744    // full: bucket storage (2*16384*48 ints) ; tab32: num0
#define N1_OFF    5309184    // tab32: num1
#define HIST_OFF  7930624    // 2*16384 (int)
#define START_OFF 7963392    // 2*16384 (int)
#define FILL_OFF  7996160    // 2*16384 (int)
#define SSRC_OFF  8028928    // full: pW tables (2*96*32 float2) ; tab32: ssrc
#define SDST_OFF  8553216    // 2*262144 (int, tab32 fallback)
#define PART_OFF  9102080    // 16384*12
#define BASE_END  9298688
// FULL path: half2 pair-table (PACKED channel order) + half key_f mirrors (PACKED)
#define TABH_OFF  9298688    // 2*64*512*192 half2 = 12582912 float-slots
#define TABH_END  (TABH_OFF + 2*64*NG*192)
#define KFH_OFF   TABH_END   // 2*16e6 halfs = 16e6 float-slots
#define FULL_END  (KFH_OFF + 16000000)
// TAB32 fallback: fp32 table (R4 proven, original layout)
#define TAB_OFF   9298688
#define TAB_END   (TAB_OFF + 2*64*NG*192)

struct __align__(16) H2x4 { __half2 x, y, z, w; };
struct __align__(8)  H2x2 { __half2 x, y; };

// ---------------------------------------------------------------------------
// Kernel 1: prep_AQ — blocks 0..63: rt + qemb + G + qx_flat + qf_t chunk 0
// (+ zero cnt/fill). Blocks 64..65: fold pW. Blocks 66..257 (full path only):
// qf_t chunks 1..3 (3 blocks per t, R recomputed locally — independent).
// ---------------------------------------------------------------------------
__global__ __launch_bounds__(256) void prep_AQ(
    const float* __restrict__ Ts, const float* __restrict__ timev,
    const float* __restrict__ W_qt, const float* __restrict__ b_qt,
    const float* __restrict__ W1_r, const float* __restrict__ b1_r,
    const float* __restrict__ query_x, const float* __restrict__ query_f,
    const float* __restrict__ p00, const float* __restrict__ prest,
    const float* __restrict__ Ws_tp, const float* __restrict__ Wv_tp,
    float* __restrict__ ws, int* __restrict__ histp, int* __restrict__ fillp,
    float2* __restrict__ pW, int split)
{
  int b = blockIdx.x, tid = threadIdx.x;

  if (b >= 64 && b < 66) {
    int ih = b - 64;
    const float* Ws = Ws_tp + ih*96*33;
    const float* Wv = Wv_tp + ih*96*32;
    const float* pp = p00 + ih*64;
    const float* pr = prest + ih*128;
    for (int idx = tid; idx < 3072; idx += 256) {
      int c2 = idx >> 5, o = idx & 31;
      float ps = (c2 < 64) ? pp[c2] : pr[c2];
      float pv = (c2 < 64) ? pr[c2] : pr[c2 + 32];
      pW[ih*3072 + idx] = make_float2(ps * Ws[c2*33 + o + 1], pv * Wv[c2*32 + o]);
    }
    return;
  }

  __shared__ float Rs[12];
  int t, el0, el1;

  if (b < 64) {
    t = b;
    el0 = 0;
    el1 = split ? 10240 : 40960;
  } else {
    int x = b - 66;
    t = x / 3;
    int ch = 1 + (x - t*3);
    el0 = ch*10240;
    el1 = el0 + 10240;
  }

  if (tid == 0) {
    float qw = Ts[t*7+0], qx = Ts[t*7+1], qy = Ts[t*7+2], qz = Ts[t*7+3];
    float nrm = sqrtf(qw*qw + qx*qx + qy*qy + qz*qz);
    qw /= nrm; qx /= nrm; qy /= nrm; qz /= nrm;
    Rs[0] = 1.f - 2.f*(qy*qy + qz*qz); Rs[1] = 2.f*(qx*qy - qw*qz); Rs[2] = 2.f*(qx*qz + qw*qy);
    Rs[3] = 2.f*(qx*qy + qw*qz); Rs[4] = 1.f - 2.f*(qx*qx + qz*qz); Rs[5] = 2.f*(qy*qz - qw*qx);
    Rs[6] = 2.f*(qx*qz - qw*qy); Rs[7] = 2.f*(qy*qz + qw*qx); Rs[8] = 1.f - 2.f*(qx*qx + qy*qy);
    Rs[9] = Ts[t*7+4]; Rs[10] = Ts[t*7+5]; Rs[11] = Ts[t*7+6];
  }

  if (b < 64) {
    __shared__ float te[128];
    __shared__ float qe[128];

    {
      int base = t*512;
      histp[base + tid] = 0;        histp[base + 256 + tid] = 0;
      fillp[base + tid] = 0;        fillp[base + 256 + tid] = 0;
    }

    float tt = timev[t];
    if (tid < 128) {
      int h = tid & 63;
      float fr = __expf(-logf(10000.f) * (float)h / 63.f);
      float a = tt * fr;
      te[tid] = (tid < 64) ? sinf(a) : cosf(a);
    }
    __syncthreads();
    if (tid == 0) {
      float* R = ws + R_OFF + t*9;
      #pragma unroll
      for (int i = 0; i < 9; i++) R[i] = Rs[i];
      ws[TR_OFF + t*3 + 0] = Rs[9];
      ws[TR_OFF + t*3 + 1] = Rs[10];
      ws[TR_OFF + t*3 + 2] = Rs[11];
    }
    if (tid < 128) {
      float acc = b_qt[tid];
      #pragma unroll 4
      for (int k = 0; k < 128; k++) acc += te[k] * W_qt[k*128 + tid];
      qe[tid] = acc;
    }
    __syncthreads();
    if (tid < 128) {
      int sidx = tid >> 6, o = tid & 63;
      const float* W1 = W1_r + sidx*136*64;
      float acc = b1_r[sidx*64 + o];
      #pragma unroll 4
      for (int k = 0; k < 128; k++) acc += qe[k] * W1[(8+k)*64 + o];
      ws[G_OFF + sidx*4096 + t*64 + o] = acc;
    }
    for (int el = tid; el < 768; el += 256) {
      int q = el / 3, i = el - q*3;
      const float* x = query_x + q*3;
      ws[QX_OFF + t*768 + el] = Rs[i*3+0]*x[0] + Rs[i*3+1]*x[1] + Rs[i*3+2]*x[2] + Rs[9+i];
    }
  } else {
    __syncthreads();
  }

  for (int el = el0 + tid; el < el1; el += 256) {
    int q = el / 160, j = el - q*160;
    float v;
    if (j < 64) {
      v = query_f[q*160 + j];
    } else {
      int c = (j - 64) / 3, i = (j - 64) - c*3;
      const float* qv = query_f + q*160 + 64 + c*3;
      v = Rs[i*3+0]*qv[0] + Rs[i*3+1]*qv[1] + Rs[i*3+2]*qv[2];
    }
    ws[QF_OFF + (size_t)t*40960 + el] = v;
  }
}

// ---------------------------------------------------------------------------
// Kernel 2: conv_bucket — conv_kf (blocks <6250) + padded-CSR bucket fill
// (homogeneous low-VGPR branches; R15-proven)
// ---------------------------------------------------------------------------
__global__ __launch_bounds__(256) void conv_bucket(
    const float* __restrict__ kf0, const float* __restrict__ kf1,
    __half* __restrict__ o0, __half* __restrict__ o1,
    const int* __restrict__ es0, const int* __restrict__ ed0,
    const int* __restrict__ es1, const int* __restrict__ ed1,
    int* __restrict__ cnt, int* __restrict__ bucket)
{
  __shared__ float stage[2560];
  int sc = blockIdx.y, tid = threadIdx.x;
  if (blockIdx.x < 6250) {
    const float* src = sc ? kf1 : kf0;
    __half* dst = sc ? o1 : o0;
    size_t base = (size_t)blockIdx.x * 2560;
    #pragma unroll
    for (int it = 0; it < 10; it++) stage[it*256 + tid] = src[base + it*256 + tid];
    __syncthreads();
    #pragma unroll
    for (int it = 0; it < 10; it++) {
      int idx = it*256 + tid;
      int n = idx / 160;
      int j = idx - n*160;
      int orig;
      if (j < 32) {
        orig = 32 + j;
      } else {
        int qq = (j - 32) >> 2, rr = (j - 32) & 3;
        orig = (rr < 3) ? (64 + 3*qq + rr) : qq;
      }
      dst[base + idx] = __float2half_rn(stage[n*160 + orig]);
    }
  } else {
    int b = blockIdx.x - 6250;
    const int* es = sc ? es1 : es0;
    const int* ed = sc ? ed1 : ed0;
    int e = b*256 + tid;
    int d = ed[e];
    int pos = atomicAdd(cnt + sc*NN + d, 1);
    if (pos < BKT) bucket[((size_t)sc*NN + d)*BKT + pos] = es[e];
  }
}

// ---------------------------------------------------------------------------
// Kernel 3: build_tabH — packed half2 pair-table (standalone; own VGPR budget)
// ---------------------------------------------------------------------------
__global__ __launch_bounds__(256) void build_tabH(
    const float* __restrict__ W1_r, const float* __restrict__ W2_r,
    const float* __restrict__ b2_r, const float* __restrict__ Gall,
    __half2* __restrict__ tabH)
{
  int t = blockIdx.x, gblk = blockIdx.y, sidx = blockIdx.z;
  const float* W1 = W1_r + sidx*136*64;
  const float* W2 = W2_r + sidx*64*192;
  const float* b2 = b2_r + sidx*192;
  const float* G  = Gall + sidx*4096 + t*64;
  __shared__ float hb[4][64];
  __shared__ float rows[5][192];
  int tid = threadIdx.x;
  int gl = gblk*64;

  if (tid < 64) {
    float r = (float)gl * DRF;
    float a = G[tid];
    #pragma unroll
    for (int j = 0; j < 8; j++) {
      float dd = r - (float)j*(4.f/7.f);
      a += __expf(-4.f*dd*dd) * W1[j*64 + tid];
    }
    hb[0][tid] = a / (1.f + __expf(-a));
  }
  __syncthreads();
  if (tid < 192) {
    float acc = b2[tid];
    #pragma unroll
    for (int k = 0; k < 64; k++) acc += hb[0][k] * W2[k*192 + tid];
    rows[0][tid] = acc;
  }
  __syncthreads();

  for (int g = 0; g < 16; g++) {
    {
      int gg = tid >> 6, k = tid & 63;
      float r = (float)(gl + 4*g + 1 + gg) * DRF;
      float a = G[k];
      #pragma unroll
      for (int j = 0; j < 8; j++) {
        float dd = r - (float)j*(4.f/7.f);
        a += __expf(-4.f*dd*dd) * W1[j*64 + k];
      }
      hb[gg][k] = a / (1.f + __expf(-a));
    }
    __syncthreads();
    #pragma unroll
    for (int it = 0; it < 3; it++) {
      int item = it*256 + tid;
      int rr = item / 192, o = item - rr*192;
      float acc = b2[o];
      #pragma unroll
      for (int k = 0; k < 64; k++) acc += hb[rr][k] * W2[k*192 + o];
      rows[1 + rr][o] = acc;
    }
    __syncthreads();
    __half2* T = tabH + ((size_t)(sidx*64 + t)*NG + gl + 4*g)*192;
    #pragma unroll
    for (int it = 0; it < 3; it++) {
      int item = it*256 + tid;
      int pr = item / 192, o = item - pr*192;
      int src = (o < 64) ? o : (64 + 32*((o-64)&3) + ((o-64)>>2));
      T[(size_t)pr*192 + o] = __floats2half2_rn(rows[pr][src], rows[pr+1][src]);
    }
    __syncthreads();
    if (tid < 192) rows[0][tid] = rows[4][tid];
    __syncthreads();
  }
}

// ---------------------------------------------------------------------------
// Kernel 4 (FULL path): node-centric edge accumulation + tp_head inline
// (R13-proven form: no software pipeline; TLP hides gather latency)
// ---------------------------------------------------------------------------
__global__ __launch_bounds__(256) void edge_head_kernel(
    const float* __restrict__ kx0, const float* __restrict__ kx1,
    const __half* __restrict__ kfh0, const __half* __restrict__ kfh1,
    const int* __restrict__ bucket, const int* __restrict__ hist,
    const __half2* __restrict__ tabH, const float* __restrict__ qx_flat,
    const float* __restrict__ qf_t, const float* __restrict__ Rtab,
    const float* __restrict__ query_x, const float* __restrict__ query_w,
    const float2* __restrict__ pW,
    float* __restrict__ part)
{
  __shared__ float sb[4][96];
  __shared__ float vb[4][96][3];
  int wid = threadIdx.x >> 6, lane = threadIdx.x & 63;
  int n = blockIdx.x*4 + wid;
  int t = n >> 8, q = n & 255;
  int lo = lane & 31;
  bool isHi = lane >= 32;
  float qxv0 = qx_flat[n*3+0], qxv1 = qx_flat[n*3+1], qxv2 = qx_flat[n*3+2];
  int ksAddr = isHi ? (lane - 32) : (32 + 4*lane + 3);

  float kfs = 0.f, kv0 = 0.f, kv1 = 0.f, kv2 = 0.f;

  #pragma unroll 1
  for (int sc = 0; sc < 2; sc++) {
    const float* key_x = sc ? kx1 : kx0;
    const __half* kfb  = sc ? kfh1 : kfh0;
    const __half2* Tb  = tabH + (size_t)sc*(64*NG*192);
    int cntT = hist[sc*NN + n];
    int cnt = cntT < BKT ? cntT : BKT;
    const int* srcp = bucket + ((size_t)sc*NN + n)*BKT;

    float accs = 0.f, accM = 0.f, av0 = 0.f, av1 = 0.f, av2 = 0.f;

    for (int e = 0; e < cnt; e += 2) {
      int eMy = e + (isHi ? 1 : 0);
      float wMy = (eMy < cnt) ? 1.f : 0.f;
      int eCl = (eMy < cnt) ? eMy : (cnt - 1);
      int sMy = srcp[eCl];

      float rel0 = key_x[sMy*3+0] - qxv0;
      float rel1 = key_x[sMy*3+1] - qxv1;
      float rel2 = key_x[sMy*3+2] - qxv2;
      float r = sqrtf(rel0*rel0 + rel1*rel1 + rel2*rel2);
      float rinv = 1.f / (r + 1e-8f);
      float dir0 = rel0*rinv, dir1 = rel1*rinv, dir2 = rel2*rinv;
      float x = fminf(r, RMAXF) * INV_DRF;
      int i = (int)x; if (i > NG-2) i = NG-2;
      float fMy = x - (float)i;
      int rowMy = t*NG + i;

      int   sOth   = __shfl_xor(sMy, 32);
      int   rowOth = __shfl_xor(rowMy, 32);
      float fOth   = __shfl_xor(fMy, 32);
      float wOth   = isHi ? 1.f : ((e + 1 < cnt) ? 1.f : 0.f);

      const __half2* thMy  = Tb + (size_t)rowMy*192;
      const __half2* thOth = Tb + (size_t)rowOth*192;
      const __half*  kfMy  = kfb + (size_t)sMy*160;
      const __half*  kfOth = kfb + (size_t)sOth*160;

      // scalar channel `lane`, both edges
      float2 u0m = __half22float2(thMy[lane]);
      float a0m = fmaf(fMy, u0m.y - u0m.x, u0m.x);
      float ksm = __half2float(kfMy[ksAddr]);
      float2 u0o = __half22float2(thOth[lane]);
      float a0o = fmaf(fOth, u0o.y - u0o.x, u0o.x);
      float kso = __half2float(kfOth[ksAddr]);
      accs += wMy*a0m*ksm + wOth*a0o*kso;

      // vec channel `lo` of MY edge: one 16B + one 8B packed load
      H2x4 pq = *(const H2x4*)(thMy + 64 + 4*lo);
      float2 ua = __half22float2(pq.x);
      float2 ub = __half22float2(pq.y);
      float2 uc = __half22float2(pq.z);
      float2 ud = __half22float2(pq.w);
      float a1 = fmaf(fMy, ua.y - ua.x, ua.x);
      float a2 = fmaf(fMy, ub.y - ub.x, ub.x);
      float a3 = fmaf(fMy, uc.y - uc.x, uc.x);
      float a4 = fmaf(fMy, ud.y - ud.x, ud.x);
      H2x2 kq = *(const H2x2*)(kfMy + 32 + 4*lo);
      float2 kA = __half22float2(kq.x);
      float2 kB = __half22float2(kq.y);
      float k0 = kA.x * wMy, k1 = kA.y * wMy, k2 = kB.x * wMy, ksv = kB.y * wMy;
      float dt = k0*dir0 + k1*dir1 + k2*dir2;
      accM += a3*dt;
      float cr0 = k1*dir2 - k2*dir1;
      float cr1 = k2*dir0 - k0*dir2;
      float cr2 = k0*dir1 - k1*dir0;
      float sv = a2*ksv;
      av0 += a1*k0 + sv*dir0 + a4*cr0;
      av1 += a1*k1 + sv*dir1 + a4*cr1;
      av2 += a1*k2 + sv*dir2 + a4*cr2;
    }

    float mT  = accM + __shfl_down(accM, 32);
    float v0T = av0 + __shfl_down(av0, 32);
    float v1T = av1 + __shfl_down(av1, 32);
    float v2T = av2 + __shfl_down(av2, 32);
    float ic = 1.f / ((float)cntT + 1e-8f);
    kfs += ic * (accs + (isHi ? 0.f : mT));
    kv0 += ic * v0T; kv1 += ic * v1T; kv2 += ic * v2T;
  }

  // ---- tp_head phase 1 ----
  const float* qf = qf_t + (size_t)n*160;
  sb[wid][lane] = kfs * qf[lane];
  if (!isHi) {
    float qs = qf[lane];
    float q0 = qf[64+3*lane+0], q1 = qf[64+3*lane+1], q2 = qf[64+3*lane+2];
    sb[wid][64+lane] = kv0*q0 + kv1*q1 + kv2*q2;
    vb[wid][lane][0] = kv0*qs;  vb[wid][lane][1] = kv1*qs;  vb[wid][lane][2] = kv2*qs;
    vb[wid][32+lane][0] = kfs*q0; vb[wid][32+lane][1] = kfs*q1; vb[wid][32+lane][2] = kfs*q2;
    vb[wid][64+lane][0] = kv1*q2 - kv2*q1;
    vb[wid][64+lane][1] = kv2*q0 - kv0*q2;
    vb[wid][64+lane][2] = kv0*q1 - kv1*q0;
  }
  __syncthreads();

  // ---- tp_head phase 2 (prefolded weights) ----
  int ih = lane >> 5, o = lane & 31;
  const float2* pWh = pW + ih*3072 + o;
  float g = 0.f, v0 = 0.f, v1 = 0.f, v2 = 0.f;
  #pragma unroll 4
  for (int c2 = 0; c2 < 96; c2++) {
    float2 wv = pWh[c2*32];
    g += sb[wid][c2] * wv.x;
    v0 += vb[wid][c2][0] * wv.y;
    v1 += vb[wid][c2][1] * wv.y;
    v2 += vb[wid][c2][2] * wv.y;
  }
  g = 1.f / (1.f + __expf(-g));
  v0 *= g; v1 *= g; v2 *= g;
  #pragma unroll
  for (int m = 16; m >= 1; m >>= 1) {
    v0 += __shfl_xor(v0, m, 32);
    v1 += __shfl_xor(v1, m, 32);
    v2 += __shfl_xor(v2, m, 32);
  }
  if (o == 0) {
    v0 *= (1.f/32.f); v1 *= (1.f/32.f); v2 *= (1.f/32.f);
    const float* R = Rtab + t*9;
    float r0 = R[0]*v0 + R[3]*v1 + R[6]*v2;
    float r1 = R[1]*v0 + R[4]*v1 + R[7]*v2;
    float r2 = R[2]*v0 + R[5]*v1 + R[8]*v2;
    float w = query_w[q];
    float* pout = part + (size_t)n*12;
    if (ih == 0) {
      pout[0] = w*r0; pout[1] = w*r1; pout[2] = w*r2;
      float x0 = query_x[q*3+0], x1 = query_x[q*3+1], x2 = query_x[q*3+2];
      pout[3] = w*(x1*r2 - x2*r1);
      pout[4] = w*(x2*r0 - x0*r2);
      pout[5] = w*(x0*r1 - x1*r0);
    } else {
      pout[6] = w*r0; pout[7] = w*r1; pout[8] = w*r2;
    }
  }
}

// ===========================================================================
// TAB32 fallback kernels (R4-proven path)
// ===========================================================================
__global__ __launch_bounds__(256) void hist_kernel(
    const int* __restrict__ ed0, const int* __restrict__ ed1,
    int* __restrict__ hist)
{
  int sc = blockIdx.y;
  const int* ed = sc ? ed1 : ed0;
  int e = blockIdx.x*256 + threadIdx.x;
  atomicAdd(hist + sc*NN + ed[e], 1);
}

__global__ __launch_bounds__(1024) void scan_kernel(
    const int* __restrict__ hist, int* __restrict__ start)
{
  int sc = blockIdx.x;
  const int* h = hist + sc*NN;
  int* st = start + sc*NN;
  __shared__ int lds[1024];
  int tid = threadIdx.x;
  int loc[16]; int s = 0;
  #pragma unroll
  for (int j = 0; j < 16; j++) { loc[j] = s; s += h[tid*16 + j]; }
  lds[tid] = s;
  __syncthreads();
  for (int off = 1; off < 1024; off <<= 1) {
    int v = lds[tid];
    int u = (tid >= off) ? lds[tid - off] : 0;
    __syncthreads();
    lds[tid] = v + u;
    __syncthreads();
  }
  int base = lds[tid] - s;
  #pragma unroll
  for (int j = 0; j < 16; j++) st[tid*16 + j] = base + loc[j];
}

__global__ __launch_bounds__(256) void scatter_kernel(
    const int* __restrict__ es0, const int* __restrict__ ed0,
    const int* __restrict__ es1, const int* __restrict__ ed1,
    const int* __restrict__ start, int* __restrict__ fill,
    int* __restrict__ ssrc, int* __restrict__ sdst)
{
  int sc = blockIdx.y;
  const int* es = sc ? es1 : es0;
  const int* ed = sc ? ed1 : ed0;
  int e = blockIdx.x*256 + threadIdx.x;
  int d = ed[e];
  int pos = start[sc*NN + d] + atomicAdd(fill + sc*NN + d, 1);
  ssrc[sc*EE + pos] = es[e];
  sdst[sc*EE + pos] = d;
}

__global__ __launch_bounds__(256) void build_tab(
    const float* __restrict__ W1_r, const float* __restrict__ W2_r,
    const float* __restrict__ b2_r, const float* __restrict__ Gall,
    float* __restrict__ tab)
{
  int t = blockIdx.x, gblk = blockIdx.y, sidx = blockIdx.z;
  const float* W1 = W1_r + sidx*136*64;
  const float* W2 = W2_r + sidx*64*192;
  const float* b2 = b2_r + sidx*192;
  const float* G  = Gall + sidx*4096 + t*64;
  float* T = tab + (((size_t)sidx*64 + t)*NG)*192;
  __shared__ float hb[4][64];
  int tid = threadIdx.x;
  for (int g4 = 0; g4 < 16; g4++) {
    int gl = gblk*64 + g4*4;
    {
      int gg = tid >> 6;
      int k  = tid & 63;
      float r = (float)(gl + gg) * DRF;
      float a = G[k];
      #pragma unroll
      for (int j = 0; j < 8; j++) {
        float dd = r - (float)j*(4.f/7.f);
        a += __expf(-4.f*dd*dd) * W1[j*64 + k];
      }
      hb[gg][k] = a / (1.f + __expf(-a));
    }
    __syncthreads();
    #pragma unroll
    for (int it = 0; it < 3; it++) {
      int item = it*256 + tid;
      int gg = item / 192;
      int o  = item - gg*192;
      float acc = b2[o];
      #pragma unroll
      for (int k = 0; k < 64; k++) acc += hb[gg][k] * W2[k*192 + o];
      T[(size_t)(gl + gg)*192 + o] = acc;
    }
    __syncthreads();
  }
}

#define SEGRED(v) { float _t; \
  _t = __shfl_down(v, 1);  v += mm0 ? _t : 0.f; \
  _t = __shfl_down(v, 2);  v += mm1 ? _t : 0.f; \
  _t = __shfl_down(v, 4);  v += mm2 ? _t : 0.f; \
  _t = __shfl_down(v, 8);  v += mm3 ? _t : 0.f; \
  _t = __shfl_down(v, 16); v += mm4 ? _t : 0.f; \
  _t = __shfl_down(v, 32); v += mm5 ? _t : 0.f; }

#define SEGMASKS() \
  int dn; \
  dn = __shfl_down(d, 1);  bool mm0 = (lane + 1  < 64) && (dn == d); \
  dn = __shfl_down(d, 2);  bool mm1 = (lane + 2  < 64) && (dn == d); \
  dn = __shfl_down(d, 4);  bool mm2 = (lane + 4  < 64) && (dn == d); \
  dn = __shfl_down(d, 8);  bool mm3 = (lane + 8  < 64) && (dn == d); \
  dn = __shfl_down(d, 16); bool mm4 = (lane + 16 < 64) && (dn == d); \
  dn = __shfl_down(d, 32); bool mm5 = (lane + 32 < 64) && (dn == d); \
  int dp = __shfl_up(d, 1); \
  bool head = (lane == 0) || (dp != d);

#define INTERP4(dst, off) { \
  float4 _A = *(const float4*)(t0 + (off)); \
  float4 _B = *(const float4*)(t1 + (off)); \
  dst[0] = _A.x + f*(_B.x - _A.x); \
  dst[1] = _A.y + f*(_B.y - _A.y); \
  dst[2] = _A.z + f*(_B.z - _A.z); \
  dst[3] = _A.w + f*(_B.w - _A.w); }

__global__ __launch_bounds__(256) void edge_tab_kernel(
    const float* __restrict__ kx0, const float* __restrict__ kf0,
    const float* __restrict__ kx1, const float* __restrict__ kf1,
    const int* __restrict__ ssrc, const int* __restrict__ sdst,
    const float* __restrict__ tab, const float* __restrict__ qx_flat,
    float* __restrict__ num0, float* __restrict__ num1)
{
  int sc = blockIdx.y;
  const float* key_x = sc ? kx1 : kx0;
  const float* key_f = sc ? kf1 : kf0;
  const float* Tb = tab + (size_t)sc*64*NG*192;
  float* numbuf = sc ? num1 : num0;

  int p = blockIdx.x*256 + threadIdx.x;
  int lane = threadIdx.x & 63;
  int s = ssrc[sc*EE + p], d = sdst[sc*EE + p];

  const float* qx = qx_flat + d*3;
  float rel0 = key_x[s*3+0] - qx[0];
  float rel1 = key_x[s*3+1] - qx[1];
  float rel2 = key_x[s*3+2] - qx[2];
  float r = sqrtf(rel0*rel0 + rel1*rel1 + rel2*rel2);
  float rinv = 1.f / (r + 1e-8f);
  float dir0 = rel0*rinv, dir1 = rel1*rinv, dir2 = rel2*rinv;

  int t = d >> 8;
  float x = fminf(r, RMAXF) * INV_DRF;
  int i = (int)x; if (i > NG-2) i = NG-2;
  float f = x - (float)i;
  const float* t0 = Tb + ((size_t)(t*NG + i))*192;
  const float* t1 = t0 + 192;

  SEGMASKS();

  const float* kf = key_f + (size_t)s * 160;
  float* nrow = numbuf + (size_t)d * 160;

  #pragma unroll 1
  for (int cq = 0; cq < 8; cq++) {
    int c = 4*cq;
    float a0v[4], a1v[4], a2v[4], a3v[4], a4v[4];
    INTERP4(a0v, c);
    INTERP4(a1v, 64 + c);
    INTERP4(a2v, 96 + c);
    INTERP4(a3v, 128 + c);
    INTERP4(a4v, 160 + c);
    float4 ksq = *(const float4*)(kf + c);
    float ksv[4] = {ksq.x, ksq.y, ksq.z, ksq.w};
    const float* kvp = kf + 64 + 3*c;
    float2 v0 = *(const float2*)(kvp + 0);
    float2 v1 = *(const float2*)(kvp + 2);
    float2 v2 = *(const float2*)(kvp + 4);
    float2 v3 = *(const float2*)(kvp + 6);
    float2 v4 = *(const float2*)(kvp + 8);
    float2 v5 = *(const float2*)(kvp + 10);
    float kvx[4] = {v0.x, v1.y, v3.x, v4.y};
    float kvy[4] = {v0.y, v2.x, v3.y, v5.x};
    float kvz[4] = {v1.x, v2.y, v4.x, v5.y};
    #pragma unroll
    for (int u = 0; u < 4; u++) {
      float ks = ksv[u];
      float k0 = kvx[u], k1 = kvy[u], k2 = kvz[u];
      float dt = k0*dir0 + k1*dir1 + k2*dir2;
      float ms = a0v[u]*ks + a3v[u]*dt;
      float cr0 = k1*dir2 - k2*dir1;
      float cr1 = k2*dir0 - k0*dir2;
      float cr2 = k0*dir1 - k1*dir0;
      float sv = a2v[u]*ks;
      float m0 = a1v[u]*k0 + sv*dir0 + a4v[u]*cr0;
      float m1 = a1v[u]*k1 + sv*dir1 + a4v[u]*cr1;
      float m2 = a1v[u]*k2 + sv*dir2 + a4v[u]*cr2;
      SEGRED(ms); SEGRED(m0); SEGRED(m1); SEGRED(m2);
      if (head) {
        int cc = c + u;
        atomicAdd(nrow + cc, ms);
        atomicAdd(nrow + 64 + 3*cc + 0, m0);
        atomicAdd(nrow + 64 + 3*cc + 1, m1);
        atomicAdd(nrow + 64 + 3*cc + 2, m2);
      }
    }
  }
  #pragma unroll 1
  for (int cq = 0; cq < 8; cq++) {
    int c = 32 + 4*cq;
    float a0v[4];
    INTERP4(a0v, c);
    float4 ksq = *(const float4*)(kf + c);
    float ksv[4] = {ksq.x, ksq.y, ksq.z, ksq.w};
    #pragma unroll
    for (int u = 0; u < 4; u++) {
      float ms = a0v[u]*ksv[u];
      SEGRED(ms);
      if (head) atomicAdd(nrow + c + u, ms);
    }
  }
}

__global__ __launch_bounds__(256) void head_kernel(
    const float* __restrict__ num0, const float* __restrict__ num1,
    const int* __restrict__ h0, const int* __restrict__ h1c,
    const float* __restrict__ qf_t, const float* __restrict__ Rtab,
    const float* __restrict__ query_x, const float* __restrict__ query_w,
    const float* __restrict__ p00, const float* __restrict__ prest,
    const float* __restrict__ Ws_tp, const float* __restrict__ Wv_tp,
    float* __restrict__ part)
{
  int wid = threadIdx.x >> 6;
  int lane = threadIdx.x & 63;
  int n = blockIdx.x*4 + wid;
  int t = n >> 8, q = n & 255;
  __shared__ float sb[4][96];
  __shared__ float vb[4][96][3];
  const float* n0 = num0 + (size_t)n*160;
  const float* n1 = num1 + (size_t)n*160;
  const float* qf = qf_t + (size_t)n*160;
  float ic0 = 1.f / ((float)h0[n] + 1e-8f);
  float ic1 = 1.f / ((float)h1c[n] + 1e-8f);
  int c = lane;
  if (c < 64) sb[wid][c] = (n0[c]*ic0 + n1[c]*ic1) * qf[c];
  if (c < 32) {
    float ks = n0[c]*ic0 + n1[c]*ic1;
    float qs = qf[c];
    float k0 = n0[64+3*c+0]*ic0 + n1[64+3*c+0]*ic1;
    float k1 = n0[64+3*c+1]*ic0 + n1[64+3*c+1]*ic1;
    float k2 = n0[64+3*c+2]*ic0 + n1[64+3*c+2]*ic1;
    float q0 = qf[64+3*c+0], q1 = qf[64+3*c+1], q2 = qf[64+3*c+2];
    sb[wid][64+c] = k0*q0 + k1*q1 + k2*q2;
    vb[wid][c][0] = k0*qs;  vb[wid][c][1] = k1*qs;  vb[wid][c][2] = k2*qs;
    vb[wid][32+c][0] = ks*q0;  vb[wid][32+c][1] = ks*q1;  vb[wid][32+c][2] = ks*q2;
    vb[wid][64+c][0] = k1*q2 - k2*q1;
    vb[wid][64+c][1] = k2*q0 - k0*q2;
    vb[wid][64+c][2] = k0*q1 - k1*q0;
  }
  __syncthreads();

  int i = lane >> 5, o = lane & 31;
  const float* Ws = Ws_tp + i*96*33;
  const float* Wv = Wv_tp + i*96*32;
  const float* pp = p00 + i*64;
  const float* pr = prest + i*128;
  float g = 0.f, v0 = 0.f, v1 = 0.f, v2 = 0.f;
  for (int c2 = 0; c2 < 96; c2++) {
    float ps = (c2 < 64) ? pp[c2] : pr[c2];
    float pv = (c2 < 64) ? pr[c2] : pr[c2 + 32];
    g += sb[wid][c2] * ps * Ws[c2*33 + o + 1];
    float pw = pv * Wv[c2*32 + o];
    v0 += vb[wid][c2][0] * pw;
    v1 += vb[wid][c2][1] * pw;
    v2 += vb[wid][c2][2] * pw;
  }
  g = 1.f / (1.f + __expf(-g));
  v0 *= g; v1 *= g; v2 *= g;
  #pragma unroll
  for (int m = 16; m >= 1; m >>= 1) {
    v0 += __shfl_xor(v0, m, 32);
    v1 += __shfl_xor(v1, m, 32);
    v2 += __shfl_xor(v2, m, 32);
  }
  if (o == 0) {
    v0 *= (1.f/32.f); v1 *= (1.f/32.f); v2 *= (1.f/32.f);
    const float* R = Rtab + t*9;
    float r0 = R[0]*v0 + R[3]*v1 + R[6]*v2;
    float r1 = R[1]*v0 + R[4]*v1 + R[7]*v2;
    float r2 = R[2]*v0 + R[5]*v1 + R[8]*v2;
    float w = query_w[q];
    float* pout = part + (size_t)n*12;
    if (i == 0) {
      pout[0] = w*r0; pout[1] = w*r1; pout[2] = w*r2;
      float x0 = query_x[q*3+0], x1 = query_x[q*3+1], x2 = query_x[q*3+2];
      pout[3] = w*(x1*r2 - x2*r1);
      pout[4] = w*(x2*r0 - x0*r2);
      pout[5] = w*(x0*r1 - x1*r0);
    } else {
      pout[6] = w*r0; pout[7] = w*r1; pout[8] = w*r2;
    }
  }
}

// ---------------------------------------------------------------------------
// Kernel 5: reduce partials over q (256 per template)
// ---------------------------------------------------------------------------
__global__ __launch_bounds__(256) void final_kernel(
    const float* __restrict__ part, float* __restrict__ out)
{
  int t = blockIdx.x, q = threadIdx.x;
  const float* pr = part + ((size_t)(t*256 + q))*12;
  float v[9];
  #pragma unroll
  for (int i = 0; i < 9; i++) v[i] = pr[i];
  #pragma unroll
  for (int m = 32; m >= 1; m >>= 1) {
    #pragma unroll
    for (int i = 0; i < 9; i++) v[i] += __shfl_down(v[i], m);
  }
  __shared__ float lds[4][9];
  int w = q >> 6, l = q & 63;
  if (l == 0) {
    #pragma unroll
    for (int i = 0; i < 9; i++) lds[w][i] = v[i];
  }
  __syncthreads();
  if (q == 0) {
    float o[9];
    #pragma unroll
    for (int i = 0; i < 9; i++) o[i] = lds[0][i] + lds[1][i] + lds[2][i] + lds[3][i];
    out[t*3+0] = o[3] + o[6];
    out[t*3+1] = o[4] + o[7];
    out[t*3+2] = o[5] + o[8];
    out[192 + t*3+0] = o[0];
    out[192 + t*3+1] = o[1];
    out[192 + t*3+2] = o[2];
  }
}

// ---------------------------------------------------------------------------
extern "C" void kernel_launch(void* const* d_in, const int* in_sizes, int n_in,
                              void* d_out, int out_size, void* d_ws, size_t ws_size,
                              hipStream_t stream)
{
  const float* Ts      = (const float*)d_in[0];
  const float* timev   = (const float*)d_in[1];
  const float* query_x = (const float*)d_in[2];
  const float* query_f = (const float*)d_in[3];
  const float* query_w = (const float*)d_in[4];
  const float* key_x_0 = (const float*)d_in[5];
  const float* key_f_0 = (const float*)d_in[6];
  const float* key_x_1 = (const float*)d_in[7];
  const float* key_f_1 = (const float*)d_in[8];
  const int*   es0     = (const int*)d_in[9];
  const int*   ed0     = (const int*)d_in[10];
  const int*   es1     = (const int*)d_in[11];
  const int*   ed1     = (const int*)d_in[12];
  const float* W_qt    = (const float*)d_in[13];
  const float* b_qt    = (const float*)d_in[14];
  const float* W1_r    = (const float*)d_in[15];
  const float* b1_r    = (const float*)d_in[16];
  const float* W2_r    = (const float*)d_in[17];
  const float* b2_r    = (const float*)d_in[18];
  const float* p00     = (const float*)d_in[19];
  const float* prest   = (const float*)d_in[20];
  const float* Ws_tp   = (const float*)d_in[21];
  const float* Wv_tp   = (const float*)d_in[22];
  float* ws  = (float*)d_ws;
  float* out = (float*)d_out;

  int* histp  = (int*)(ws + HIST_OFF);
  int* startp = (int*)(ws + START_OFF);
  int* fillp  = (int*)(ws + FILL_OFF);
  int* ssrcp  = (int*)(ws + SSRC_OFF);
  int* sdstp  = (int*)(ws + SDST_OFF);
  int* bucketp = (int*)(ws + N0_OFF);
  float2* pWp  = (float2*)(ws + SSRC_OFF);

  bool full  = ws_size >= (size_t)FULL_END * sizeof(float);
  bool tab32 = !full && ws_size >= (size_t)TAB_END * sizeof(float);

  if (full) {
    __half* kfh0 = (__half*)(ws + KFH_OFF);
    __half* kfh1 = kfh0 + 16000000;
    __half2* tabH = (__half2*)(ws + TABH_OFF);

    prep_AQ<<<258, 256, 0, stream>>>(Ts, timev, W_qt, b_qt, W1_r, b1_r,
                                     query_x, query_f, p00, prest, Ws_tp, Wv_tp,
                                     ws, histp, fillp, pWp, 1);
    conv_bucket<<<dim3(7274, 2), 256, 0, stream>>>(
        key_f_0, key_f_1, kfh0, kfh1,
        es0, ed0, es1, ed1, histp, bucketp);
    build_tabH<<<dim3(64, 8, 2), 256, 0, stream>>>(
        W1_r, W2_r, b2_r, ws + G_OFF, tabH);
    edge_head_kernel<<<4096, 256, 0, stream>>>(
        key_x_0, key_x_1, kfh0, kfh1,
        bucketp, histp, tabH, ws + QX_OFF,
        ws + QF_OFF, ws + R_OFF,
        query_x, query_w, pWp,
        ws + PART_OFF);
  } else if (tab32) {
    hipMemsetAsync(ws + N0_OFF, 0, (size_t)(2*NN*160) * sizeof(float), stream);
    prep_AQ<<<64, 256, 0, stream>>>(Ts, timev, W_qt, b_qt, W1_r, b1_r,
                                    query_x, query_f, p00, prest, Ws_tp, Wv_tp,
                                    ws, histp, fillp, (float2*)(ws + QE_OFF), 0);
    hist_kernel<<<dim3(1024, 2), 256, 0, stream>>>(ed0, ed1, histp);
    scan_kernel<<<2, 1024, 0, stream>>>(histp, startp);
    scatter_kernel<<<dim3(1024, 2), 256, 0, stream>>>(
        es0, ed0, es1, ed1, startp, fillp, ssrcp, sdstp);
    build_tab<<<dim3(64, 8, 2), 256, 0, stream>>>(
        W1_r, W2_r, b2_r, ws + G_OFF, ws + TAB_OFF);
    edge_tab_kernel<<<dim3(1024, 2), 256, 0, stream>>>(
        key_x_0, key_f_0, key_x_1, key_f_1,
        ssrcp, sdstp, ws + TAB_OFF, ws + QX_OFF,
        ws + N0_OFF, ws + N1_OFF);
    head_kernel<<<4096, 256, 0, stream>>>(
        ws + N0_OFF, ws + N1_OFF, histp, histp + NN,
        ws + QF_OFF, ws + R_OFF,
        query_x, query_w, p00, prest, Ws_tp, Wv_tp, ws + PART_OFF);
  }

  final_kernel<<<64, 256, 0, stream>>>(ws + PART_OFF, out);
}